// Round 5
// baseline (574.093 us; speedup 1.0000x reference)
//
#include <hip/hip_runtime.h>

// ---------------------------------------------------------------------------
// HardwareOptimizedQuantumLLM  (B=4, S=1024, D=512, V=8192, SCALES={1,2,4,8,16}, WIN=8)
//
// R9b: resubmit of R9 (round-4 bench was an infra failure, no counters).
// e-layer fusion: k_elayer = row-stripe GEMM (16 rows x 512 cols/block,
// 8 waves, B streamed from L2 with 2-deep reg prefetch) + fused residual +
// LN2 epilogue (16-lane shfl reduce + cross-wave LDS table). Removes 3
// post_res launches + h round-trip (24 MB). 10 -> 7 dispatches.
// ---------------------------------------------------------------------------

#define DEV __device__ __forceinline__
typedef unsigned short u16;
typedef __bf16 bf16x8 __attribute__((ext_vector_type(8)));
typedef float f32x4 __attribute__((ext_vector_type(4)));

static constexpr int S = 1024;
static constexpr int D = 512;
static constexpr int KCAT = 1088;   // 512 ctx + 512 lc + 5 msc + 1 sem + 1 const + 57 pad

DEV u16 f2bf(float f) {            // fp32 -> bf16 (RNE)
  unsigned u = __float_as_uint(f);
  return (u16)((u + 0x7fffu + ((u >> 16) & 1u)) >> 16);
}
DEV float bf2f(u16 v) { return __uint_as_float((unsigned)v << 16); }
DEV float gelu(float x) { return 0.5f * x * (1.f + erff(x * 0.70710678118654752f)); }
DEV float wredx(float v) {         // butterfly: all lanes get the wave sum
#pragma unroll
  for (int m = 32; m; m >>= 1) v += __shfl_xor(v, m, 64);
  return v;
}
DEV float qred(float v) {          // sum over quads (lanes x^1, x^2)
  v += __shfl_xor(v, 1, 64);
  v += __shfl_xor(v, 2, 64);
  return v;
}

// ---------------- k_front: [0,1024) dots | [1024,2080) pre | [2080,2656) wbig ----
// dots v6: pair-interleaved LDS layout; 2 anchors/lane share 10 row loads.
static constexpr int CP = 132;
__global__ __launch_bounds__(256) void k_front(
    const float* __restrict__ emb, const float* __restrict__ mask,
    float* __restrict__ ph, float* __restrict__ cmacc,
    const float* __restrict__ sim, const int* __restrict__ tok,
    float* __restrict__ dots_raw, float* __restrict__ normsq,
    const float* __restrict__ W0, const float* __restrict__ W1,
    const float* __restrict__ W2, const float* __restrict__ Wf,
    const float* __restrict__ wctx, const float* __restrict__ Wsc,
    const float* __restrict__ Wsm, const float* __restrict__ bsc,
    const float* __restrict__ bsm, const float* __restrict__ bcx,
    u16* __restrict__ T0, u16* __restrict__ T1, u16* __restrict__ T2,
    u16* __restrict__ wcatT, float* __restrict__ ctx_acc,
    float* __restrict__ sm_acc) {
  __shared__ __align__(16) float smem[9360];   // dots 36*65 f32x4 | wbig 64x65
  __shared__ int stok[72];
  int blk = blockIdx.x, tid = threadIdx.x;

  if (blk < 1024) {                 // ---------------- dots ----------------
    int bx = blk >> 4, cyb = blk & 15;
    int b = bx >> 4, g0 = (bx & 15) * 64, gidx = b * S + g0;
    if (tid < 72) {
      int pp = g0 + tid;
      stok[tid] = (pp < S) ? tok[b * S + pp] : -1;
    }
    __syncthreads();
    const float4* sim4 = (const float4*)sim;
    f32x4* sT4 = (f32x4*)smem;
    int wave = tid >> 6, lane = tid & 63;
    int p = lane & 31, h = lane >> 5;
    int qb = wave * 8 + h * 4;
    const f32x4* bj[10];
#pragma unroll
    for (int j = 0; j < 10; ++j)
      bj[j] = sT4 + (p + (j >> 1)) * 65 + 2 * qb + (j & 1);
    f32x4 ac0[9] = {}, ac1[9] = {};
    for (int cc = 0; cc < 4; ++cc) {
      int cy = cyb * 4 + cc;
#pragma unroll
      for (int it = 0; it < 9; ++it) {          // 72 rows x 32 float4
        int u = it * 256 + tid, r = u >> 5, q = u & 31;
        int tk = stok[r];
        float4 v = make_float4(0.f, 0.f, 0.f, 0.f);
        if (tk >= 0) v = sim4[(size_t)tk * 2048 + cy * 32 + q];
        f32x4 vv = {v.x, v.y, v.z, v.w};
        sT4[(r >> 1) * 65 + 2 * q + (r & 1)] = vv;
      }
      __syncthreads();
#pragma unroll
      for (int c4 = 0; c4 < 4; ++c4) {
        f32x4 v0 = bj[0][2 * c4], v1 = bj[1][2 * c4], v2 = bj[2][2 * c4],
              v3 = bj[3][2 * c4], v4 = bj[4][2 * c4], v5 = bj[5][2 * c4],
              v6 = bj[6][2 * c4], v7 = bj[7][2 * c4], v8 = bj[8][2 * c4],
              v9 = bj[9][2 * c4];
        ac0[8] += v0 * v0;  ac1[8] += v1 * v1;
        ac0[0] += v0 * v1;  ac1[0] += v1 * v2;
        ac0[1] += v0 * v2;  ac1[1] += v1 * v3;
        ac0[2] += v0 * v3;  ac1[2] += v1 * v4;
        ac0[3] += v0 * v4;  ac1[3] += v1 * v5;
        ac0[4] += v0 * v5;  ac1[4] += v1 * v6;
        ac0[5] += v0 * v6;  ac1[5] += v1 * v7;
        ac0[6] += v0 * v7;  ac1[6] += v1 * v8;
        ac0[7] += v0 * v8;  ac1[7] += v1 * v9;
      }
      __syncthreads();
    }
    float* red = smem;               // [w][9][h][64] = 4608 floats
#pragma unroll
    for (int s = 0; s < 9; ++s) {
      f32x4 a = ac0[s], c = ac1[s];
      red[(wave * 9 + s) * 128 + h * 64 + 2 * p]     = a[0] + a[1] + a[2] + a[3];
      red[(wave * 9 + s) * 128 + h * 64 + 2 * p + 1] = c[0] + c[1] + c[2] + c[3];
    }
    __syncthreads();
    for (int u = tid; u < 576; u += 256) {
      int s = u >> 6, a = u & 63;
      float v = 0.f;
#pragma unroll
      for (int wh = 0; wh < 8; ++wh)
        v += red[((wh >> 1) * 9 + s) * 128 + (wh & 1) * 64 + a];
      if (s < 8) atomicAdd(&dots_raw[(size_t)(gidx + a) * 8 + s], v);
      else       atomicAdd(&normsq[gidx + a], v);
    }
    return;
  }

  if (blk < 2080) {                 // ---------------- pre ----------------
    int blk2 = blk - 1024;
    if (blk2 < 1024) {
      int idx = blk2 * 256 + tid;
#pragma unroll
      for (int r = 0; r < 2; ++r, idx += 262144) {
        float4 v = ((const float4*)emb)[idx];
        float4 o;
        o.x = tanhf(v.x); o.y = tanhf(v.y); o.z = tanhf(v.z); o.w = tanhf(v.w);
        ((float4*)ph)[idx] = o;
      }
    } else {
      int r = blk2 - 1024, b = r >> 3, chunk = r & 7;
      float a0 = 0.f, a1 = 0.f;
      for (int s = chunk * 128; s < chunk * 128 + 128; ++s) {
        float m = mask[b * S + s];
        const float* row = emb + (size_t)(b * S + s) * D;
        a0 += row[tid] * m; a1 += row[tid + 256] * m;
      }
      atomicAdd(cmacc + b * D + tid, a0);
      atomicAdd(cmacc + b * D + tid + 256, a1);
    }
    return;
  }

  // ---------------- wbig ----------------
  int blk2 = blk - 2080;
  if (blk2 < 256) {
    int z = blk2 >> 6, rem = blk2 & 63;
    const float* src = z == 0 ? W0 : z == 1 ? W1 : z == 2 ? W2 : Wf + (size_t)1536 * 512;
    int r0 = (rem >> 3) * 64, c0 = (rem & 7) * 64;
    int tr = tid >> 6, tc = tid & 63;
#pragma unroll 4
    for (int i = 0; i < 16; ++i)
      smem[(tr + i * 4) * 65 + tc] = src[(size_t)(r0 + tr + i * 4) * 512 + c0 + tc];
    __syncthreads();
#pragma unroll 4
    for (int i = 0; i < 16; ++i) {
      int n = c0 + tr + i * 4, k = r0 + tc;
      u16 v = f2bf(smem[tc * 65 + tr + i * 4]);
      if (z == 3) wcatT[(size_t)n * KCAT + 512 + k] = v;
      else (z == 0 ? T0 : z == 1 ? T1 : T2)[(size_t)n * 512 + k] = v;
    }
  } else if (blk2 < 512) {
    int rem = blk2 - 256;
    int n = (rem & 1) * 256 + tid;
    int kbase = ((rem & 63) >> 1) * 16;
    int j0 = (rem >> 6) * 128;
    float acc[16] = {};
    for (int j = j0; j < j0 + 128; ++j) {
      float wf3 = Wf[(size_t)(1024 + j) * 512 + n];
#pragma unroll
      for (int kk = 0; kk < 16; ++kk) acc[kk] += wctx[(size_t)(kbase + kk) * 512 + j] * wf3;
    }
#pragma unroll
    for (int kk = 0; kk < 16; ++kk)
      atomicAdd(&ctx_acc[(size_t)(kbase + kk) * 512 + n], acc[kk]);
  } else {
    int rem = blk2 - 512;
    int n = (rem & 1) * 256 + tid;
    int j0 = (rem >> 1) * 16;
    float a0 = 0.f, a1 = 0.f, a2 = 0.f, a3 = 0.f, a4 = 0.f, au = 0.f, ac = 0.f;
    for (int j = j0; j < j0 + 16; ++j) {
      float wf1 = Wf[(size_t)j * 512 + n];
      float wf2 = Wf[(size_t)(512 + j) * 512 + n];
      float wf3 = Wf[(size_t)(1024 + j) * 512 + n];
      a0 += Wsc[j] * wf1; a1 += Wsc[512 + j] * wf1; a2 += Wsc[1024 + j] * wf1;
      a3 += Wsc[1536 + j] * wf1; a4 += Wsc[2048 + j] * wf1;
      au += Wsm[j] * wf2;
      ac += bsc[j] * wf1 + bsm[j] * wf2 + bcx[j] * wf3;
    }
    atomicAdd(&sm_acc[0 * 512 + n], a0);
    atomicAdd(&sm_acc[1 * 512 + n], a1);
    atomicAdd(&sm_acc[2 * 512 + n], a2);
    atomicAdd(&sm_acc[3 * 512 + n], a3);
    atomicAdd(&sm_acc[4 * 512 + n], a4);
    atomicAdd(&sm_acc[5 * 512 + n], au);
    atomicAdd(&sm_acc[6 * 512 + n], ac);
  }
}

// ---------------- k_mid: [0,512) coh | [512,578) packfin ----------------
static constexpr int CP2 = 68;
__global__ __launch_bounds__(256) void k_mid(const float* __restrict__ ph,
    const float* __restrict__ dots_raw, const float* __restrict__ normsq,
    float* __restrict__ msc_raw, float* __restrict__ semacc,
    const float* __restrict__ ctx_acc, const float* __restrict__ sm_acc,
    const float* __restrict__ bfu, u16* __restrict__ wcatT) {
  __shared__ __align__(16) float smem[7072];   // coh: sP 5984 + sw2 1088 | packfin 64x65
  int blk = blockIdx.x, tid = threadIdx.x;

  if (blk < 512) {                  // ---------------- coh ----------------
    float* sP = smem;
    float* sw2 = smem + 88 * CP2;   // 5984
    int bx = blk >> 3, dy = blk & 7;
    int b = bx >> 4, g0 = (bx & 15) * 64;
    const float4* ph4 = (const float4*)ph;
#pragma unroll
    for (int it = 0; it < 6; ++it) {           // 88 rows x 16 float4 = 1408
      int u = it * 256 + tid;
      if (u < 1408) {
        int r = u >> 4, q = u & 15;
        int gr = g0 - 8 + r;
        gr = gr < 0 ? 0 : (gr > S - 1 ? S - 1 : gr);
        float4 v = ph4[(size_t)(b * S + gr) * 128 + dy * 16 + q];
        *(float4*)&sP[r * CP2 + 4 * q] = v;
      }
    }
    for (int u = tid; u < 1088; u += 256) {    // swin table 64 anchors x 17
      int a = u / 17, oi = u - a * 17;
      int i = g0 + a, o = oi - 8, j = i + o;
      int idx = b * S + i;
      float v = 0.f;
      if (j >= 0 && j < S) {
        if (o == 0) v = 1.f;
        else {
          float dr = (o > 0) ? dots_raw[(size_t)idx * 8 + o - 1]
                             : dots_raw[(size_t)(idx + o) * 8 + (-o - 1)];
          float ni = fmaxf(sqrtf(normsq[idx]), 1e-12f);
          float nj = fmaxf(sqrtf(normsq[idx + o]), 1e-12f);
          v = dr / (ni * nj);
        }
      }
      sw2[u] = v;
    }
    __syncthreads();
    int ar = tid >> 2, dq = tid & 3;
    int i = g0 + ar, idx = b * S + i;
    int jmax = S - 1 - i; if (jmax > 15) jmax = 15;
    float swr[17];
#pragma unroll
    for (int oi = 0; oi < 17; ++oi) swr[oi] = sw2[ar * 17 + oi];
    float a0 = 0.f, a1 = 0.f, a2 = 0.f, a3 = 0.f, a4 = 0.f, asem = 0.f;
#pragma unroll 2
    for (int dd = 0; dd < 16; ++dd) {
      int d = dq + 4 * dd;
      const float* pb = &sP[(ar + 8) * CP2 + d];   // row i
      float sp = 0.f, sc = 0.f, ss = 0.f;
#pragma unroll
      for (int j = 0; j < 16; ++j) {
        float x = (j <= jmax) ? pb[j * CP2] : 0.f;
        sp += x; sc += __cosf(x); ss += __sinf(x);
        if (j == 0) a0 += __cosf(sp) * sc + __sinf(sp) * ss;
        else if (j == 1)  { float wm = sp * 0.5f;    a1 += __cosf(wm) * (sc * 0.5f)    + __sinf(wm) * (ss * 0.5f); }
        else if (j == 3)  { float wm = sp * 0.25f;   a2 += __cosf(wm) * (sc * 0.25f)   + __sinf(wm) * (ss * 0.25f); }
        else if (j == 7)  { float wm = sp * 0.125f;  a3 += __cosf(wm) * (sc * 0.125f)  + __sinf(wm) * (ss * 0.125f); }
        else if (j == 15) { float wm = sp * 0.0625f; a4 += __cosf(wm) * (sc * 0.0625f) + __sinf(wm) * (ss * 0.0625f); }
      }
      float p0 = pb[0];
      const float* qb = &sP[ar * CP2 + d];
#pragma unroll
      for (int oi = 0; oi < 17; ++oi) {
        int j = i + oi - 8;
        bool valid = (j >= 0) && (j < S);
        float pj = qb[oi * CP2];
        asem += valid ? __cosf((p0 - pj) * swr[oi]) : 0.f;
      }
    }
    a0 = qred(a0); a1 = qred(a1); a2 = qred(a2); a3 = qred(a3); a4 = qred(a4);
    asem = qred(asem);
    if (dq == 0) {
      float* mr = msc_raw + (size_t)idx * 5;
      atomicAdd(mr + 0, a0); atomicAdd(mr + 1, a1); atomicAdd(mr + 2, a2);
      atomicAdd(mr + 3, a3); atomicAdd(mr + 4, a4);
      atomicAdd(semacc + i, asem);
    }
    return;
  }

  // ---------------- packfin ----------------
  int blk2 = blk - 512;
  if (blk2 < 64) {
    int r0 = (blk2 >> 3) * 64, c0 = (blk2 & 7) * 64;
    int tr = tid >> 6, tc = tid & 63;
#pragma unroll 4
    for (int i = 0; i < 16; ++i)
      smem[(tr + i * 4) * 65 + tc] = ctx_acc[(size_t)(r0 + tr + i * 4) * 512 + c0 + tc];
    __syncthreads();
#pragma unroll 4
    for (int i = 0; i < 16; ++i)
      wcatT[(size_t)(c0 + tr + i * 4) * KCAT + r0 + tc] = f2bf(smem[tc * 65 + tr + i * 4]);
  } else {
    int n = (blk2 - 64) * 256 + tid;
    u16* row = wcatT + (size_t)n * KCAT;
#pragma unroll
    for (int s = 0; s < 6; ++s) row[1024 + s] = f2bf(sm_acc[s * 512 + n]);
    row[1030] = f2bf(sm_acc[6 * 512 + n] + bfu[n]);
    for (int k = 1031; k < KCAT; ++k) row[k] = 0;
  }
}

// ---------------- build Xcat (bf16): [cos(emb-cmean) | lc | msc | sem | 1 | 0] ----------------
__global__ __launch_bounds__(256) void k_xcat(const float* __restrict__ emb,
    const float* __restrict__ cmacc, const float* __restrict__ msc_raw,
    const float* __restrict__ semacc, u16* __restrict__ xcat) {
  int idx = blockIdx.x, b = idx >> 10, i = idx & 1023, tid = threadIdx.x;
  const float* erow = emb + (size_t)idx * D;
  u16* orow = xcat + (size_t)idx * KCAT;
  for (int c = tid; c < KCAT; c += 256) {
    float v;
    if (c < 512) {
      v = __cosf(erow[c] - cmacc[b * D + c] * (1.f / 1024.f));
    } else if (c < 1024) {
      int d = c - 512;
      v = (i < S - 1) ? __cosf(erow[D + d] - erow[d]) : 0.f;
    } else if (c < 1029) {
      int s = c - 1024, req = (1 << s) - 1;    // scale s valid iff jmax >= 2^s-1
      v = (S - 1 - i >= req) ? msc_raw[(size_t)idx * 5 + s] * (1.f / 512.f) : 0.f;
    } else if (c == 1029) {
      int cnt = ((i < 8) ? i : 8) + ((S - 1 - i < 8) ? (S - 1 - i) : 8) + 1;
      v = semacc[i] / (4.f * (float)cnt * 512.f);
    } else if (c == 1030) {
      v = 1.f;
    } else v = 0.f;
    orow[c] = f2bf(v);
  }
}

// ---------------- bf16 MFMA GEMM (gemm1 only): C[M,512] = A @ BT^T ----------------
__global__ __launch_bounds__(256) void k_gemm(const u16* __restrict__ A,
    const u16* __restrict__ BT, float* __restrict__ C, int K) {
  __shared__ __align__(16) u16 sA[64 * 72];
  __shared__ __align__(16) u16 sB[64 * 72];
  int tid = threadIdx.x, wave = tid >> 6, lane = tid & 63;
  int m0 = blockIdx.x * 64, n0 = blockIdx.y * 64;
  int lr = tid >> 2, lc = (tid & 3) * 8;
  int q8 = (lane >> 4) * 8, l15 = lane & 15;
  const u16* Ap = A + (size_t)(m0 + lr) * K + lc;
  const u16* Bp = BT + (size_t)(n0 + lr) * K + lc;
  uint4 ra0 = *(const uint4*)(Ap);
  uint4 ra1 = *(const uint4*)(Ap + 32);
  uint4 rb0 = *(const uint4*)(Bp);
  uint4 rb1 = *(const uint4*)(Bp + 32);
  f32x4 acc[4] = {};
  for (int k0 = 0; k0 < K; k0 += 64) {
    *(uint4*)&sA[lr * 72 + lc]      = ra0;
    *(uint4*)&sA[lr * 72 + lc + 32] = ra1;
    *(uint4*)&sB[lr * 72 + lc]      = rb0;
    *(uint4*)&sB[lr * 72 + lc + 32] = rb1;
    __syncthreads();
    if (k0 + 64 < K) {               // prefetch next tile into regs
      ra0 = *(const uint4*)(Ap + k0 + 64);
      ra1 = *(const uint4*)(Ap + k0 + 96);
      rb0 = *(const uint4*)(Bp + k0 + 64);
      rb1 = *(const uint4*)(Bp + k0 + 96);
    }
    int row = wave * 16 + l15;
    bf16x8 af0 = *(const bf16x8*)&sA[row * 72 + q8];
    bf16x8 af1 = *(const bf16x8*)&sA[row * 72 + 32 + q8];
#pragma unroll
    for (int f = 0; f < 4; ++f) {
      bf16x8 b0 = *(const bf16x8*)&sB[(f * 16 + l15) * 72 + q8];
      bf16x8 b1 = *(const bf16x8*)&sB[(f * 16 + l15) * 72 + 32 + q8];
      acc[f] = __builtin_amdgcn_mfma_f32_16x16x32_bf16(af0, b0, acc[f], 0, 0, 0);
      acc[f] = __builtin_amdgcn_mfma_f32_16x16x32_bf16(af1, b1, acc[f], 0, 0, 0);
    }
    __syncthreads();
  }
  int r0 = m0 + wave * 16 + (lane >> 4) * 4;
#pragma unroll
  for (int f = 0; f < 4; ++f) {
    int col = n0 + f * 16 + l15;
#pragma unroll
    for (int r = 0; r < 4; ++r)
      C[(size_t)(r0 + r) * 512 + col] = acc[f][r];
  }
}

// ---------------- fused e-layer: h = t @ We^T + b; x += 0.1*gelu(h); t' = LN(x) ----
// Block = 16 rows x 512 cols, 512 threads (8 waves x 64 cols). A (t, bf16)
// staged in LDS [16][520] (row stride 260 dw == 4 mod 32: 2-way max). B (We^T,
// 0.5 MB) streamed from L2 with 2-deep register prefetch. Epilogue: residual +
// LN fully in-block (16-lane shfl_xor reduce + 16x8 cross-wave LDS table).
__global__ __launch_bounds__(512) void k_elayer(const u16* __restrict__ A,
    const u16* __restrict__ BT, const float* __restrict__ bias,
    float* __restrict__ x, u16* __restrict__ t, float* __restrict__ out,
    const float* __restrict__ g, const float* __restrict__ bb, int final_) {
  __shared__ __align__(16) u16 sA[16 * 520];
  __shared__ float sred[2][16][8];
  int tid = threadIdx.x, w = tid >> 6, lane = tid & 63;
  int l15 = lane & 15, q = lane >> 4, q8 = q * 8;
  int m0 = blockIdx.x * 16;
#pragma unroll
  for (int it = 0; it < 2; ++it) {            // stage A: 16 rows x 64 chunks
    int u = it * 512 + tid, row = u >> 6, c8 = (u & 63) * 8;
    *(uint4*)&sA[row * 520 + c8] = *(const uint4*)(A + (size_t)(m0 + row) * 512 + c8);
  }
  __syncthreads();
  const u16* Bb = BT + (size_t)(w * 64 + l15) * 512 + q8;
  uint4 p0[4], p1[4];
#pragma unroll
  for (int f = 0; f < 4; ++f) {
    p0[f] = *(const uint4*)(Bb + f * 8192);
    p1[f] = *(const uint4*)(Bb + f * 8192 + 32);
  }
  f32x4 acc[4] = {};
  for (int k0 = 0; k0 < 512; k0 += 64) {
    uint4 c0[4], c1[4];
#pragma unroll
    for (int f = 0; f < 4; ++f) { c0[f] = p0[f]; c1[f] = p1[f]; }
    if (k0 + 64 < 512) {
#pragma unroll
      for (int f = 0; f < 4; ++f) {
        p0[f] = *(const uint4*)(Bb + f * 8192 + k0 + 64);
        p1[f] = *(const uint4*)(Bb + f * 8192 + k0 + 96);
      }
    }
    bf16x8 af0 = *(const bf16x8*)&sA[l15 * 520 + k0 + q8];
    bf16x8 af1 = *(const bf16x8*)&sA[l15 * 520 + k0 + 32 + q8];
#pragma unroll
    for (int f = 0; f < 4; ++f) {
      acc[f] = __builtin_amdgcn_mfma_f32_16x16x32_bf16(af0, *(bf16x8*)&c0[f], acc[f], 0, 0, 0);
      acc[f] = __builtin_amdgcn_mfma_f32_16x16x32_bf16(af1, *(bf16x8*)&c1[f], acc[f], 0, 0, 0);
    }
  }
  // epilogue: residual + row stats
  float xv[4][4], s[4] = {}, ss[4] = {};
#pragma unroll
  for (int f = 0; f < 4; ++f) {
    int col = w * 64 + f * 16 + l15;
    float bv = bias[col];
#pragma unroll
    for (int r = 0; r < 4; ++r) {
      int row = q * 4 + r;
      float xn = x[(size_t)(m0 + row) * 512 + col] + 0.1f * gelu(acc[f][r] + bv);
      xv[f][r] = xn; s[r] += xn; ss[r] += xn * xn;
    }
  }
#pragma unroll
  for (int r = 0; r < 4; ++r) {
#pragma unroll
    for (int m = 1; m <= 8; m <<= 1) {
      s[r]  += __shfl_xor(s[r],  m, 64);
      ss[r] += __shfl_xor(ss[r], m, 64);
    }
  }
  if (l15 == 0) {
#pragma unroll
    for (int r = 0; r < 4; ++r) {
      sred[0][q * 4 + r][w] = s[r];
      sred[1][q * 4 + r][w] = ss[r];
    }
  }
  __syncthreads();
  float mr[4], ir[4];
#pragma unroll
  for (int r = 0; r < 4; ++r) {
    int row = q * 4 + r;
    float st = 0.f, sst = 0.f;
#pragma unroll
    for (int ww = 0; ww < 8; ++ww) { st += sred[0][row][ww]; sst += sred[1][row][ww]; }
    float m = st * (1.f / 512.f);
    mr[r] = m;
    ir[r] = rsqrtf(sst * (1.f / 512.f) - m * m + 1e-5f);
  }
#pragma unroll
  for (int f = 0; f < 4; ++f) {
    int col = w * 64 + f * 16 + l15;
    float gv = g[col], bbv = bb[col];
#pragma unroll
    for (int r = 0; r < 4; ++r) {
      int row = q * 4 + r;
      float nv = (xv[f][r] - mr[r]) * ir[r] * gv + bbv;
      if (final_) {
        out[(size_t)(m0 + row) * 512 + col] = nv;
      } else {
        x[(size_t)(m0 + row) * 512 + col] = xv[f][r];
        t[(size_t)(m0 + row) * 512 + col] = f2bf(nv);
      }
    }
  }
}

// ---------------- post-fuse v2: wave-per-row, x = gelu(LN1(y1)); t = bf16(LN2(x)) ----
__global__ __launch_bounds__(256) void k_post_y1(const float* __restrict__ y,
    float* __restrict__ x, u16* __restrict__ t,
    const float* __restrict__ g1, const float* __restrict__ b1,
    const float* __restrict__ g2, const float* __restrict__ b2) {
  int tid = threadIdx.x, w = tid >> 6, lane = tid & 63;
  int row = blockIdx.x * 4 + w;
  size_t base = (size_t)row * 512 + lane * 8;
  int gb = lane * 8;
  float4 va = *(const float4*)(y + base);
  float4 vb = *(const float4*)(y + base + 4);
  float v[8] = {va.x, va.y, va.z, va.w, vb.x, vb.y, vb.z, vb.w};
  float s = 0.f, ss = 0.f;
#pragma unroll
  for (int k = 0; k < 8; ++k) { s += v[k]; ss += v[k] * v[k]; }
  s = wredx(s); ss = wredx(ss);
  float m = s * (1.f / 512.f);
  float inv = rsqrtf(ss * (1.f / 512.f) - m * m + 1e-5f);
  float4 gA = *(const float4*)(g1 + gb), gB = *(const float4*)(g1 + gb + 4);
  float4 bA = *(const float4*)(b1 + gb), bB = *(const float4*)(b1 + gb + 4);
  float gv[8] = {gA.x, gA.y, gA.z, gA.w, gB.x, gB.y, gB.z, gB.w};
  float bv[8] = {bA.x, bA.y, bA.z, bA.w, bB.x, bB.y, bB.z, bB.w};
  float xv[8];
  float s2 = 0.f, ss2 = 0.f;
#pragma unroll
  for (int k = 0; k < 8; ++k) {
    xv[k] = gelu((v[k] - m) * inv * gv[k] + bv[k]);
    s2 += xv[k]; ss2 += xv[k] * xv[k];
  }
  *(float4*)(x + base)     = make_float4(xv[0], xv[1], xv[2], xv[3]);
  *(float4*)(x + base + 4) = make_float4(xv[4], xv[5], xv[6], xv[7]);
  s2 = wredx(s2); ss2 = wredx(ss2);
  m = s2 * (1.f / 512.f);
  inv = rsqrtf(ss2 * (1.f / 512.f) - m * m + 1e-5f);
  float4 g2A = *(const float4*)(g2 + gb), g2B = *(const float4*)(g2 + gb + 4);
  float4 b2A = *(const float4*)(b2 + gb), b2B = *(const float4*)(b2 + gb + 4);
  float g2v[8] = {g2A.x, g2A.y, g2A.z, g2A.w, g2B.x, g2B.y, g2B.z, g2B.w};
  float b2v[8] = {b2A.x, b2A.y, b2A.z, b2A.w, b2B.x, b2B.y, b2B.z, b2B.w};
  union { u16 us[8]; uint4 u4; } pk;
#pragma unroll
  for (int k = 0; k < 8; ++k) pk.us[k] = f2bf((xv[k] - m) * inv * g2v[k] + b2v[k]);
  *(uint4*)(t + base) = pk.u4;
}

// ---------------------------------------------------------------------------
extern "C" void kernel_launch(void* const* d_in, const int* in_sizes, int n_in,
                              void* d_out, int out_size, void* d_ws, size_t ws_size,
                              hipStream_t stream) {
  const float* emb     = (const float*)d_in[0];
  const int*   tok     = (const int*)d_in[1];
  const float* mask    = (const float*)d_in[2];
  const float* sim     = (const float*)d_in[3];
  const float* W_scale = (const float*)d_in[4];
  const float* b_scale = (const float*)d_in[5];
  const float* W_sem   = (const float*)d_in[6];
  const float* b_sem   = (const float*)d_in[7];
  const float* W_ctx   = (const float*)d_in[8];
  const float* b_ctx   = (const float*)d_in[9];
  const float* W_fuse  = (const float*)d_in[10];
  const float* b_fuse  = (const float*)d_in[11];
  const float* ln1_g = (const float*)d_in[12], *ln1_b = (const float*)d_in[13];
  const float* ln2_g = (const float*)d_in[14], *ln2_b = (const float*)d_in[15];
  const float* ln3_g = (const float*)d_in[16], *ln3_b = (const float*)d_in[17];
  const float* W_e0 = (const float*)d_in[18], *b_e0 = (const float*)d_in[19];
  const float* W_e1 = (const float*)d_in[20], *b_e1 = (const float*)d_in[21];
  const float* W_e2 = (const float*)d_in[22], *b_e2 = (const float*)d_in[23];
  float* out = (float*)d_out;

  char* w = (char*)d_ws; size_t off = 0;
  auto alloc = [&](size_t bytes) { void* p = w + off; off += (bytes + 255) & ~(size_t)255; return p; };
  float* phases = (float*)alloc((size_t)4096 * 512 * 4);
  float* hbuf   = (float*)alloc((size_t)4096 * 512 * 4);
  float* xbuf   = (float*)alloc((size_t)4096 * 512 * 4);
  u16*   tbuf   = (u16*)  alloc((size_t)4096 * 512 * 2);
  u16*   xcat   = (u16*)  alloc((size_t)4096 * KCAT * 2);
  u16*   wcatT  = (u16*)  alloc((size_t)512 * KCAT * 2);
  u16*   We0T   = (u16*)  alloc((size_t)512 * 512 * 2);
  u16*   We1T   = (u16*)  alloc((size_t)512 * 512 * 2);
  u16*   We2T   = (u16*)  alloc((size_t)512 * 512 * 2);
  // zero-init cluster (contiguous, sizes multiples of 256 B: one memset)
  float* semacc   = (float*)alloc((size_t)1024 * 4);
  float* cmacc    = (float*)alloc((size_t)4 * 512 * 4);
  float* dots_raw = (float*)alloc((size_t)4096 * 8 * 4);
  float* normsq   = (float*)alloc((size_t)4096 * 4);
  float* msc_raw  = (float*)alloc((size_t)4096 * 5 * 4);
  float* ctx_acc  = (float*)alloc((size_t)512 * 512 * 4);
  float* sm_acc   = (float*)alloc((size_t)7 * 512 * 4);
  (void)ws_size; (void)in_sizes; (void)n_in; (void)out_size;

  size_t zbytes = (size_t)(1024 + 4 * 512 + 4096 * 8 + 4096 + 4096 * 5 + 512 * 512 + 7 * 512) * 4;
  hipMemsetAsync(semacc, 0, zbytes, stream);

  k_front<<<2656, 256, 0, stream>>>(emb, mask, phases, cmacc,
                                    sim, tok, dots_raw, normsq,
                                    W_e0, W_e1, W_e2, W_fuse, W_ctx,
                                    W_scale, W_sem, b_scale, b_sem, b_ctx,
                                    We0T, We1T, We2T, wcatT, ctx_acc, sm_acc);
  k_mid<<<578, 256, 0, stream>>>(phases, dots_raw, normsq, msc_raw, semacc,
                                 ctx_acc, sm_acc, b_fuse, wcatT);

  k_xcat<<<4096, 256, 0, stream>>>(emb, cmacc, msc_raw, semacc, xcat);
  k_gemm<<<dim3(64, 8), 256, 0, stream>>>(xcat, wcatT, hbuf, KCAT);
  k_post_y1<<<1024, 256, 0, stream>>>(hbuf, xbuf, tbuf, ln1_g, ln1_b, ln2_g, ln2_b);

  k_elayer<<<256, 512, 0, stream>>>(tbuf, We0T, b_e0, xbuf, tbuf, nullptr,
                                    ln2_g, ln2_b, 0);
  k_elayer<<<256, 512, 0, stream>>>(tbuf, We1T, b_e1, xbuf, tbuf, nullptr,
                                    ln2_g, ln2_b, 0);
  k_elayer<<<256, 512, 0, stream>>>(tbuf, We2T, b_e2, xbuf, nullptr, out,
                                    ln3_g, ln3_b, 1);
}